// Round 13
// baseline (3765.768 us; speedup 1.0000x reference)
//
#include <hip/hip_runtime.h>

#define NN 100000
#define NE 1600000
#define HF 128
#define INF 16
#define NLAYERS 19
#define NB_SCAN 98  // idiv(NN,1024)

static inline int idiv(int a, int b) { return (a + b - 1) / b; }

__device__ __forceinline__ float leaky(float v) { return (v >= 0.f) ? v : 0.01f * v; }

// ---------------- preprocessing ----------------

// histogram over edge range [e0,e1)
__global__ __launch_bounds__(256) void k_deg1(const int* __restrict__ idx, int* __restrict__ deg,
                                              int e0, int e1) {
  int i = e0 + (blockIdx.x * 256 + threadIdx.x) * 4;
  if (i + 4 <= e1) {
    int4 v = *reinterpret_cast<const int4*>(idx + i);
    atomicAdd(&deg[v.x], 1);
    atomicAdd(&deg[v.y], 1);
    atomicAdd(&deg[v.z], 1);
    atomicAdd(&deg[v.w], 1);
  } else {
    for (; i < e1; ++i) atomicAdd(&deg[idx[i]], 1);
  }
}

__global__ __launch_bounds__(256) void k_norms(const int* __restrict__ dout, const int* __restrict__ din,
                                               float* __restrict__ iso, float* __restrict__ isi, int n) {
  int i = blockIdx.x * 256 + threadIdx.x;
  if (i < n) {
    iso[i] = rsqrtf((float)(dout[i] > 1 ? dout[i] : 1));
    isi[i] = rsqrtf((float)(din[i] > 1 ? din[i] : 1));
  }
}

// ---- multi-block scan (3 kernels) ----

__global__ __launch_bounds__(1024) void k_scan_part(const int* __restrict__ cnt, int* __restrict__ bsum, int n) {
  __shared__ int wsum[16];
  const int tid = threadIdx.x;
  const int lane = tid & 63;
  const int wid = tid >> 6;
  int i = blockIdx.x * 1024 + tid;
  int v = (i < n) ? cnt[i] : 0;
  int s = v;
#pragma unroll
  for (int m = 1; m < 64; m <<= 1) s += __shfl_xor(s, m, 64);
  if (lane == 0) wsum[wid] = s;
  __syncthreads();
  if (tid == 0) {
    int t = 0;
#pragma unroll
    for (int j = 0; j < 16; j++) t += wsum[j];
    bsum[blockIdx.x] = t;
  }
}

__global__ __launch_bounds__(128) void k_scan_small(const int* __restrict__ bsum, int* __restrict__ boff,
                                                    int* __restrict__ rp, int n, int nb) {
  __shared__ int ws[2];
  const int tid = threadIdx.x;
  const int lane = tid & 63;
  const int wid = tid >> 6;
  int v = (tid < nb) ? bsum[tid] : 0;
  int x = v;
#pragma unroll
  for (int off = 1; off < 64; off <<= 1) {
    int t = __shfl_up(x, off, 64);
    if (lane >= off) x += t;
  }
  if (lane == 63) ws[wid] = x;
  __syncthreads();
  int add = (wid > 0) ? ws[0] : 0;
  if (tid < nb) boff[tid] = add + x - v;
  if (tid == 127) rp[n] = ws[0] + x;
}

__global__ __launch_bounds__(1024) void k_scan_final(const int* __restrict__ cnt, const int* __restrict__ boff,
                                                     int* __restrict__ rp, int n) {
  __shared__ int wsum[16];
  const int tid = threadIdx.x;
  const int lane = tid & 63;
  const int wid = tid >> 6;
  int i = blockIdx.x * 1024 + tid;
  int v = (i < n) ? cnt[i] : 0;
  int x = v;
#pragma unroll
  for (int off = 1; off < 64; off <<= 1) {
    int t = __shfl_up(x, off, 64);
    if (lane >= off) x += t;
  }
  if (lane == 63) wsum[wid] = x;
  __syncthreads();
  if (wid == 0) {
    int s = (lane < 16) ? wsum[lane] : 0;
#pragma unroll
    for (int off = 1; off < 16; off <<= 1) {
      int t = __shfl_up(s, off, 64);
      if (lane >= off) s += t;
    }
    if (lane < 16) wsum[lane] = s;
  }
  __syncthreads();
  int woff = (wid > 0) ? wsum[wid - 1] : 0;
  if (i < n) rp[i] = boff[blockIdx.x] + woff + x - v;
}

// build packed CSR over edge range [e0,e1): cv[pos] = {col, bits(val)}
__global__ __launch_bounds__(256) void k_build(const int* __restrict__ src, const int* __restrict__ dst,
                                               const float* __restrict__ ew, const float* __restrict__ iso,
                                               const float* __restrict__ isi, const int* __restrict__ rp,
                                               int* __restrict__ cursor, int2* __restrict__ cv,
                                               int e0, int e1) {
  int i = e0 + blockIdx.x * 256 + threadIdx.x;
  if (i < e1) {
    int s = src[i], d = dst[i];
    int pos = rp[d] + atomicAdd(&cursor[d], 1);
    float v = ew[i] * iso[s] * isi[d];
    cv[pos] = make_int2(s, __float_as_int(v));
  }
}

// ---------------- layer 1 (16 feats) ----------------

__global__ __launch_bounds__(256) void k_spmm16(const float* __restrict__ x, const int* __restrict__ rp,
                                                const int2* __restrict__ cv, float* __restrict__ agg16, int n) {
  int t = blockIdx.x * 256 + threadIdx.x;
  int node = t >> 4, f = t & 15;
  if (node >= n) return;
  int e = rp[node], end = rp[node + 1];
  float a = 0.f;
  for (; e + 4 <= end; e += 4) {
    int2 q0 = cv[e], q1 = cv[e + 1], q2 = cv[e + 2], q3 = cv[e + 3];
    float x0 = x[(size_t)q0.x * INF + f];
    float x1 = x[(size_t)q1.x * INF + f];
    float x2 = x[(size_t)q2.x * INF + f];
    float x3 = x[(size_t)q3.x * INF + f];
    a = fmaf(__int_as_float(q0.y), x0, a);
    a = fmaf(__int_as_float(q1.y), x1, a);
    a = fmaf(__int_as_float(q2.y), x2, a);
    a = fmaf(__int_as_float(q3.y), x3, a);
  }
  for (; e < end; ++e) {
    int2 q = cv[e];
    a = fmaf(__int_as_float(q.y), x[(size_t)q.x * INF + f], a);
  }
  agg16[(size_t)node * INF + f] = a;
}

__global__ __launch_bounds__(256) void k_gemm16(const float* __restrict__ agg16, const float* __restrict__ W1,
                                                const float* __restrict__ b1, float* __restrict__ h, int n) {
  __shared__ float W1s[INF * HF];
  int tid = threadIdx.x;
  {
    float4* d4 = reinterpret_cast<float4*>(W1s);
    const float4* s4 = reinterpret_cast<const float4*>(W1);
    d4[tid] = s4[tid];
    d4[tid + 256] = s4[tid + 256];
  }
  __syncthreads();
  int t = blockIdx.x * 256 + tid;
  int node = t >> 7, c = t & 127;
  if (node >= n) return;
  const float* ar = agg16 + (size_t)node * INF;
  float4 a0 = *reinterpret_cast<const float4*>(ar);
  float4 a1 = *reinterpret_cast<const float4*>(ar + 4);
  float4 a2 = *reinterpret_cast<const float4*>(ar + 8);
  float4 a3 = *reinterpret_cast<const float4*>(ar + 12);
  float av[16] = {a0.x, a0.y, a0.z, a0.w, a1.x, a1.y, a1.z, a1.w,
                  a2.x, a2.y, a2.z, a2.w, a3.x, a3.y, a3.z, a3.w};
  float a = b1[c];
#pragma unroll
  for (int f = 0; f < INF; ++f) a = fmaf(av[f], W1s[f * HF + c], a);
  h[(size_t)t] = leaky(a);
}

// ---------------- hidden layers ----------------

// wave-per-node, float2 per lane, 8-deep gather pipeline (at fabric BW ceiling).
__global__ __launch_bounds__(256) void k_spmm(const float* __restrict__ h, const int* __restrict__ rp,
                                              const int2* __restrict__ cv, float* __restrict__ agg,
                                              int n0, int n1) {
  const int lane = threadIdx.x & 63;
  const int node = __builtin_amdgcn_readfirstlane(n0 + blockIdx.x * 4 + (threadIdx.x >> 6));
  if (node >= n1) return;
  const int beg = rp[node], end = rp[node + 1];
  const size_t fo = (size_t)(lane << 1);
  float ax = 0.f, ay = 0.f;
  int e = beg;
  for (; e + 8 <= end; e += 8) {
    int2 q0 = cv[e + 0], q1 = cv[e + 1], q2 = cv[e + 2], q3 = cv[e + 3];
    int2 q4 = cv[e + 4], q5 = cv[e + 5], q6 = cv[e + 6], q7 = cv[e + 7];
    float2 x0 = *reinterpret_cast<const float2*>(h + (size_t)q0.x * HF + fo);
    float2 x1 = *reinterpret_cast<const float2*>(h + (size_t)q1.x * HF + fo);
    float2 x2 = *reinterpret_cast<const float2*>(h + (size_t)q2.x * HF + fo);
    float2 x3 = *reinterpret_cast<const float2*>(h + (size_t)q3.x * HF + fo);
    float2 x4 = *reinterpret_cast<const float2*>(h + (size_t)q4.x * HF + fo);
    float2 x5 = *reinterpret_cast<const float2*>(h + (size_t)q5.x * HF + fo);
    float2 x6 = *reinterpret_cast<const float2*>(h + (size_t)q6.x * HF + fo);
    float2 x7 = *reinterpret_cast<const float2*>(h + (size_t)q7.x * HF + fo);
    ax = fmaf(__int_as_float(q0.y), x0.x, ax); ay = fmaf(__int_as_float(q0.y), x0.y, ay);
    ax = fmaf(__int_as_float(q1.y), x1.x, ax); ay = fmaf(__int_as_float(q1.y), x1.y, ay);
    ax = fmaf(__int_as_float(q2.y), x2.x, ax); ay = fmaf(__int_as_float(q2.y), x2.y, ay);
    ax = fmaf(__int_as_float(q3.y), x3.x, ax); ay = fmaf(__int_as_float(q3.y), x3.y, ay);
    ax = fmaf(__int_as_float(q4.y), x4.x, ax); ay = fmaf(__int_as_float(q4.y), x4.y, ay);
    ax = fmaf(__int_as_float(q5.y), x5.x, ax); ay = fmaf(__int_as_float(q5.y), x5.y, ay);
    ax = fmaf(__int_as_float(q6.y), x6.x, ax); ay = fmaf(__int_as_float(q6.y), x6.y, ay);
    ax = fmaf(__int_as_float(q7.y), x7.x, ax); ay = fmaf(__int_as_float(q7.y), x7.y, ay);
  }
  if (e + 4 <= end) {
    int2 q0 = cv[e + 0], q1 = cv[e + 1], q2 = cv[e + 2], q3 = cv[e + 3];
    float2 x0 = *reinterpret_cast<const float2*>(h + (size_t)q0.x * HF + fo);
    float2 x1 = *reinterpret_cast<const float2*>(h + (size_t)q1.x * HF + fo);
    float2 x2 = *reinterpret_cast<const float2*>(h + (size_t)q2.x * HF + fo);
    float2 x3 = *reinterpret_cast<const float2*>(h + (size_t)q3.x * HF + fo);
    ax = fmaf(__int_as_float(q0.y), x0.x, ax); ay = fmaf(__int_as_float(q0.y), x0.y, ay);
    ax = fmaf(__int_as_float(q1.y), x1.x, ax); ay = fmaf(__int_as_float(q1.y), x1.y, ay);
    ax = fmaf(__int_as_float(q2.y), x2.x, ax); ay = fmaf(__int_as_float(q2.y), x2.y, ay);
    ax = fmaf(__int_as_float(q3.y), x3.x, ax); ay = fmaf(__int_as_float(q3.y), x3.y, ay);
    e += 4;
  }
  if (e + 2 <= end) {
    int2 q0 = cv[e + 0], q1 = cv[e + 1];
    float2 x0 = *reinterpret_cast<const float2*>(h + (size_t)q0.x * HF + fo);
    float2 x1 = *reinterpret_cast<const float2*>(h + (size_t)q1.x * HF + fo);
    ax = fmaf(__int_as_float(q0.y), x0.x, ax); ay = fmaf(__int_as_float(q0.y), x0.y, ay);
    ax = fmaf(__int_as_float(q1.y), x1.x, ax); ay = fmaf(__int_as_float(q1.y), x1.y, ay);
    e += 2;
  }
  if (e < end) {
    int2 q0 = cv[e];
    float2 x0 = *reinterpret_cast<const float2*>(h + (size_t)q0.x * HF + fo);
    ax = fmaf(__int_as_float(q0.y), x0.x, ax); ay = fmaf(__int_as_float(q0.y), x0.y, ay);
  }
  *reinterpret_cast<float2*>(agg + (size_t)node * HF + fo) = make_float2(ax, ay);
}

// fp32 register-tiled GEMM: 64 nodes x 128 cols per block, 128 threads, 8x8 per thread.
// LDS-throughput model fix: 8x8 tile gives 128 VALU-cyc per 48 LDS-cyc per wave per k-step
// (1.5x LDS oversubscription vs 2.25x for the 4x8 shape that measured 51.4us @ 48% VALU).
// Single-buffered staging (global->reg->LDS immediately, nothing held across FMA loop).
// NO min-waves launch bound (rounds 6+11 lesson: bounds+held-regs => scratch spill).
__global__ __launch_bounds__(128) void k_gemm(const float* __restrict__ A, const float* __restrict__ W,
                                              const float* __restrict__ bias, float* __restrict__ out, int n) {
  __shared__ float As[32][68];   // [k][node], rows 272B (16B-aligned)
  __shared__ float Ws[32][132];  // [k][col]
  const int tid = threadIdx.x;
  const int n0 = blockIdx.x * 64;
  const int ty = tid >> 4;  // 0..7 -> node quads {ty*4, ty*4+32}
  const int tx = tid & 15;  // 0..15 -> col quads {tx*4, tx*4+64}
  float acc[8][8];
#pragma unroll
  for (int i = 0; i < 8; i++)
#pragma unroll
    for (int j = 0; j < 8; j++) acc[i][j] = 0.f;

  for (int kc = 0; kc < HF; kc += 32) {
    // A stage: 64 nodes x 32 k = 512 float4, 4 per thread (coalesced per node row)
#pragma unroll
    for (int p = 0; p < 4; ++p) {
      int idx = p * 128 + tid;
      int node = idx >> 3;         // 0..63
      int k4 = (idx & 7) * 4;      // 0,4,...,28
      int ng = n0 + node;
      float4 v = make_float4(0.f, 0.f, 0.f, 0.f);
      if (ng < n) v = *reinterpret_cast<const float4*>(A + (size_t)ng * HF + kc + k4);
      As[k4 + 0][node] = v.x;
      As[k4 + 1][node] = v.y;
      As[k4 + 2][node] = v.z;
      As[k4 + 3][node] = v.w;
    }
    // W stage: 32 rows x 128 cols = 1024 float4, 8 per thread (coalesced, conflict-free)
#pragma unroll
    for (int p = 0; p < 8; ++p) {
      int idx = p * 128 + tid;
      int r = idx >> 5;            // 0..31
      int c4 = (idx & 31) * 4;     // 0..124
      *reinterpret_cast<float4*>(&Ws[r][c4]) =
          *reinterpret_cast<const float4*>(W + (size_t)(kc + r) * HF + c4);
    }
    __syncthreads();
#pragma unroll
    for (int k = 0; k < 32; ++k) {
      float4 a0 = *reinterpret_cast<const float4*>(&As[k][ty * 4]);
      float4 a1 = *reinterpret_cast<const float4*>(&As[k][ty * 4 + 32]);
      float4 w0 = *reinterpret_cast<const float4*>(&Ws[k][tx * 4]);
      float4 w1 = *reinterpret_cast<const float4*>(&Ws[k][tx * 4 + 64]);
      float av[8] = {a0.x, a0.y, a0.z, a0.w, a1.x, a1.y, a1.z, a1.w};
      float wv[8] = {w0.x, w0.y, w0.z, w0.w, w1.x, w1.y, w1.z, w1.w};
#pragma unroll
      for (int i = 0; i < 8; i++)
#pragma unroll
        for (int j = 0; j < 8; j++) acc[i][j] = fmaf(av[i], wv[j], acc[i][j]);
    }
    __syncthreads();
  }

  // epilogue: node groups {ty*4+i, ty*4+32+i}, col groups {tx*4, tx*4+64}
  float4 bb0 = *reinterpret_cast<const float4*>(bias + tx * 4);
  float4 bb1 = *reinterpret_cast<const float4*>(bias + tx * 4 + 64);
  float bb[8] = {bb0.x, bb0.y, bb0.z, bb0.w, bb1.x, bb1.y, bb1.z, bb1.w};
#pragma unroll
  for (int g = 0; g < 2; ++g) {
#pragma unroll
    for (int i = 0; i < 4; ++i) {
      int node = n0 + ty * 4 + g * 32 + i;
      if (node < n) {
        int ai = g * 4 + i;
        float o[8];
#pragma unroll
        for (int j = 0; j < 8; j++) o[j] = leaky(acc[ai][j] + bb[j]);
        *reinterpret_cast<float4*>(out + (size_t)node * HF + tx * 4) = make_float4(o[0], o[1], o[2], o[3]);
        *reinterpret_cast<float4*>(out + (size_t)node * HF + tx * 4 + 64) = make_float4(o[4], o[5], o[6], o[7]);
      }
    }
  }
}

// ---------------- head ----------------

__global__ __launch_bounds__(256) void k_head(const float* __restrict__ h, const float* __restrict__ fcW,
                                              const float* __restrict__ fcb, float* __restrict__ out, int n) {
  int gw = (blockIdx.x * 256 + threadIdx.x) >> 6;
  int lane = threadIdx.x & 63;
  int node = gw * 8 + (lane >> 3);
  int part = lane & 7;
  float a0 = 0.f, a1 = 0.f, a2 = 0.f, a3 = 0.f;
  if (node < n) {
    const float* hp = h + (size_t)node * HF + part * 16;
#pragma unroll
    for (int i = 0; i < 16; i++) {
      float xv = hp[i];
      float4 wk = *reinterpret_cast<const float4*>(fcW + (part * 16 + i) * 4);
      a0 = fmaf(xv, wk.x, a0);
      a1 = fmaf(xv, wk.y, a1);
      a2 = fmaf(xv, wk.z, a2);
      a3 = fmaf(xv, wk.w, a3);
    }
  }
#pragma unroll
  for (int m = 1; m < 8; m <<= 1) {
    a0 += __shfl_xor(a0, m, 64);
    a1 += __shfl_xor(a1, m, 64);
    a2 += __shfl_xor(a2, m, 64);
    a3 += __shfl_xor(a3, m, 64);
  }
  if (part == 0 && node < n) {
    float4 o = make_float4(a0 + fcb[0], a1 + fcb[1], a2 + fcb[2], a3 + fcb[3]);
    *reinterpret_cast<float4*>(out + (size_t)node * 4) = o;
  }
}

// ---------------- launch ----------------

extern "C" void kernel_launch(void* const* d_in, const int* in_sizes, int n_in,
                              void* d_out, int out_size, void* d_ws, size_t ws_size,
                              hipStream_t stream) {
  const float* x = (const float*)d_in[0];
  const float* ew = (const float*)d_in[1];
  const int* src = (const int*)d_in[2];
  const int* dst = (const int*)d_in[3];
  const float* W1 = (const float*)d_in[4];
  const float* b1 = (const float*)d_in[5];
  const float* Wst = (const float*)d_in[6];
  const float* bst = (const float*)d_in[7];
  const float* fcW = (const float*)d_in[8];
  const float* fcb = (const float*)d_in[9];
  float* out = (float*)d_out;

  const int n = NN, e = NE;
  char* w = (char*)d_ws;
  size_t off = 0;
  auto alloc = [&](size_t bytes) {
    void* p = w + off;
    off += (bytes + 511) & ~(size_t)511;
    return p;
  };
  int* dout = (int*)alloc((size_t)n * 4);
  int* din = (int*)alloc((size_t)n * 4);
  float* iso = (float*)alloc((size_t)n * 4);
  float* isi = (float*)alloc((size_t)n * 4);
  int* rp = (int*)alloc((size_t)(n + 1) * 4);
  int* cursor = (int*)alloc((size_t)n * 4);
  int* bsum = (int*)alloc((size_t)NB_SCAN * 4);
  int* boff = (int*)alloc((size_t)NB_SCAN * 4);
  int2* cv = (int2*)alloc((size_t)e * 8);
  float* h = (float*)alloc((size_t)n * HF * 4);
  float* agg = (float*)alloc((size_t)n * HF * 4);
  float* agg16 = agg;  // reuse

  hipMemsetAsync(dout, 0, (size_t)n * 4, stream);
  hipMemsetAsync(din, 0, (size_t)n * 4, stream);
  hipMemsetAsync(cursor, 0, (size_t)n * 4, stream);

  const int eh = 800000;  // e/2, multiple of 4
  k_deg1<<<idiv(eh, 1024), 256, 0, stream>>>(src, dout, 0, eh);
  k_deg1<<<idiv(e - eh, 1024), 256, 0, stream>>>(src, dout, eh, e);
  k_deg1<<<idiv(eh, 1024), 256, 0, stream>>>(dst, din, 0, eh);
  k_deg1<<<idiv(e - eh, 1024), 256, 0, stream>>>(dst, din, eh, e);
  k_norms<<<idiv(n, 256), 256, 0, stream>>>(dout, din, iso, isi, n);

  k_scan_part<<<NB_SCAN, 1024, 0, stream>>>(din, bsum, n);
  k_scan_small<<<1, 128, 0, stream>>>(bsum, boff, rp, n, NB_SCAN);
  k_scan_final<<<NB_SCAN, 1024, 0, stream>>>(din, boff, rp, n);

  k_build<<<idiv(eh, 256), 256, 0, stream>>>(src, dst, ew, iso, isi, rp, cursor, cv, 0, eh);
  k_build<<<idiv(e - eh, 256), 256, 0, stream>>>(src, dst, ew, iso, isi, rp, cursor, cv, eh, e);

  k_spmm16<<<idiv(n * INF, 256), 256, 0, stream>>>(x, rp, cv, agg16, n);
  k_gemm16<<<idiv(n * HF, 256), 256, 0, stream>>>(agg16, W1, b1, h, n);

  // 3-way node-range split of spmm (telemetry: keeps k_gemm in rocprof top-5)
  const int s1 = 33336, s2 = 66672;  // multiples of 4
  for (int l = 0; l < NLAYERS; ++l) {
    k_spmm<<<idiv(s1 - 0, 4), 256, 0, stream>>>(h, rp, cv, agg, 0, s1);
    k_spmm<<<idiv(s2 - s1, 4), 256, 0, stream>>>(h, rp, cv, agg, s1, s2);
    k_spmm<<<idiv(n - s2, 4), 256, 0, stream>>>(h, rp, cv, agg, s2, n);
    k_gemm<<<idiv(n, 64), 128, 0, stream>>>(agg, Wst + (size_t)l * HF * HF, bst + (size_t)l * HF, h, n);
  }
  k_head<<<idiv(n * 8, 256), 256, 0, stream>>>(h, fcW, fcb, out, n);
}

// Round 14
// 3405.610 us; speedup vs baseline: 1.1058x; 1.1058x over previous
//
#include <hip/hip_runtime.h>

#define NN 100000
#define NE 1600000
#define HF 128
#define INF 16
#define NLAYERS 19
#define NB_SCAN 98  // idiv(NN,1024)

static inline int idiv(int a, int b) { return (a + b - 1) / b; }

__device__ __forceinline__ float leaky(float v) { return (v >= 0.f) ? v : 0.01f * v; }

// ---------------- preprocessing ----------------

// histogram over edge range [e0,e1)
__global__ __launch_bounds__(256) void k_deg1(const int* __restrict__ idx, int* __restrict__ deg,
                                              int e0, int e1) {
  int i = e0 + (blockIdx.x * 256 + threadIdx.x) * 4;
  if (i + 4 <= e1) {
    int4 v = *reinterpret_cast<const int4*>(idx + i);
    atomicAdd(&deg[v.x], 1);
    atomicAdd(&deg[v.y], 1);
    atomicAdd(&deg[v.z], 1);
    atomicAdd(&deg[v.w], 1);
  } else {
    for (; i < e1; ++i) atomicAdd(&deg[idx[i]], 1);
  }
}

__global__ __launch_bounds__(256) void k_norms(const int* __restrict__ dout, const int* __restrict__ din,
                                               float* __restrict__ iso, float* __restrict__ isi, int n) {
  int i = blockIdx.x * 256 + threadIdx.x;
  if (i < n) {
    iso[i] = rsqrtf((float)(dout[i] > 1 ? dout[i] : 1));
    isi[i] = rsqrtf((float)(din[i] > 1 ? din[i] : 1));
  }
}

// ---- multi-block scan (3 kernels) ----

__global__ __launch_bounds__(1024) void k_scan_part(const int* __restrict__ cnt, int* __restrict__ bsum, int n) {
  __shared__ int wsum[16];
  const int tid = threadIdx.x;
  const int lane = tid & 63;
  const int wid = tid >> 6;
  int i = blockIdx.x * 1024 + tid;
  int v = (i < n) ? cnt[i] : 0;
  int s = v;
#pragma unroll
  for (int m = 1; m < 64; m <<= 1) s += __shfl_xor(s, m, 64);
  if (lane == 0) wsum[wid] = s;
  __syncthreads();
  if (tid == 0) {
    int t = 0;
#pragma unroll
    for (int j = 0; j < 16; j++) t += wsum[j];
    bsum[blockIdx.x] = t;
  }
}

__global__ __launch_bounds__(128) void k_scan_small(const int* __restrict__ bsum, int* __restrict__ boff,
                                                    int* __restrict__ rp, int n, int nb) {
  __shared__ int ws[2];
  const int tid = threadIdx.x;
  const int lane = tid & 63;
  const int wid = tid >> 6;
  int v = (tid < nb) ? bsum[tid] : 0;
  int x = v;
#pragma unroll
  for (int off = 1; off < 64; off <<= 1) {
    int t = __shfl_up(x, off, 64);
    if (lane >= off) x += t;
  }
  if (lane == 63) ws[wid] = x;
  __syncthreads();
  int add = (wid > 0) ? ws[0] : 0;
  if (tid < nb) boff[tid] = add + x - v;
  if (tid == 127) rp[n] = ws[0] + x;
}

__global__ __launch_bounds__(1024) void k_scan_final(const int* __restrict__ cnt, const int* __restrict__ boff,
                                                     int* __restrict__ rp, int n) {
  __shared__ int wsum[16];
  const int tid = threadIdx.x;
  const int lane = tid & 63;
  const int wid = tid >> 6;
  int i = blockIdx.x * 1024 + tid;
  int v = (i < n) ? cnt[i] : 0;
  int x = v;
#pragma unroll
  for (int off = 1; off < 64; off <<= 1) {
    int t = __shfl_up(x, off, 64);
    if (lane >= off) x += t;
  }
  if (lane == 63) wsum[wid] = x;
  __syncthreads();
  if (wid == 0) {
    int s = (lane < 16) ? wsum[lane] : 0;
#pragma unroll
    for (int off = 1; off < 16; off <<= 1) {
      int t = __shfl_up(s, off, 64);
      if (lane >= off) s += t;
    }
    if (lane < 16) wsum[lane] = s;
  }
  __syncthreads();
  int woff = (wid > 0) ? wsum[wid - 1] : 0;
  if (i < n) rp[i] = boff[blockIdx.x] + woff + x - v;
}

// build packed CSR over edge range [e0,e1): cv[pos] = {col, bits(val)}
__global__ __launch_bounds__(256) void k_build(const int* __restrict__ src, const int* __restrict__ dst,
                                               const float* __restrict__ ew, const float* __restrict__ iso,
                                               const float* __restrict__ isi, const int* __restrict__ rp,
                                               int* __restrict__ cursor, int2* __restrict__ cv,
                                               int e0, int e1) {
  int i = e0 + blockIdx.x * 256 + threadIdx.x;
  if (i < e1) {
    int s = src[i], d = dst[i];
    int pos = rp[d] + atomicAdd(&cursor[d], 1);
    float v = ew[i] * iso[s] * isi[d];
    cv[pos] = make_int2(s, __float_as_int(v));
  }
}

// ---------------- layer 1 (16 feats) ----------------

__global__ __launch_bounds__(256) void k_spmm16(const float* __restrict__ x, const int* __restrict__ rp,
                                                const int2* __restrict__ cv, float* __restrict__ agg16, int n) {
  int t = blockIdx.x * 256 + threadIdx.x;
  int node = t >> 4, f = t & 15;
  if (node >= n) return;
  int e = rp[node], end = rp[node + 1];
  float a = 0.f;
  for (; e + 4 <= end; e += 4) {
    int2 q0 = cv[e], q1 = cv[e + 1], q2 = cv[e + 2], q3 = cv[e + 3];
    float x0 = x[(size_t)q0.x * INF + f];
    float x1 = x[(size_t)q1.x * INF + f];
    float x2 = x[(size_t)q2.x * INF + f];
    float x3 = x[(size_t)q3.x * INF + f];
    a = fmaf(__int_as_float(q0.y), x0, a);
    a = fmaf(__int_as_float(q1.y), x1, a);
    a = fmaf(__int_as_float(q2.y), x2, a);
    a = fmaf(__int_as_float(q3.y), x3, a);
  }
  for (; e < end; ++e) {
    int2 q = cv[e];
    a = fmaf(__int_as_float(q.y), x[(size_t)q.x * INF + f], a);
  }
  agg16[(size_t)node * INF + f] = a;
}

__global__ __launch_bounds__(256) void k_gemm16(const float* __restrict__ agg16, const float* __restrict__ W1,
                                                const float* __restrict__ b1, float* __restrict__ h, int n) {
  __shared__ float W1s[INF * HF];
  int tid = threadIdx.x;
  {
    float4* d4 = reinterpret_cast<float4*>(W1s);
    const float4* s4 = reinterpret_cast<const float4*>(W1);
    d4[tid] = s4[tid];
    d4[tid + 256] = s4[tid + 256];
  }
  __syncthreads();
  int t = blockIdx.x * 256 + tid;
  int node = t >> 7, c = t & 127;
  if (node >= n) return;
  const float* ar = agg16 + (size_t)node * INF;
  float4 a0 = *reinterpret_cast<const float4*>(ar);
  float4 a1 = *reinterpret_cast<const float4*>(ar + 4);
  float4 a2 = *reinterpret_cast<const float4*>(ar + 8);
  float4 a3 = *reinterpret_cast<const float4*>(ar + 12);
  float av[16] = {a0.x, a0.y, a0.z, a0.w, a1.x, a1.y, a1.z, a1.w,
                  a2.x, a2.y, a2.z, a2.w, a3.x, a3.y, a3.z, a3.w};
  float a = b1[c];
#pragma unroll
  for (int f = 0; f < INF; ++f) a = fmaf(av[f], W1s[f * HF + c], a);
  h[(size_t)t] = leaky(a);
}

// ---------------- hidden layers ----------------

// wave-per-node, float2 per lane, 8-deep gather pipeline (at fabric BW ceiling).
// Single dispatch per layer (telemetry split removed).
__global__ __launch_bounds__(256) void k_spmm(const float* __restrict__ h, const int* __restrict__ rp,
                                              const int2* __restrict__ cv, float* __restrict__ agg, int n) {
  const int lane = threadIdx.x & 63;
  const int node = __builtin_amdgcn_readfirstlane(blockIdx.x * 4 + (threadIdx.x >> 6));
  if (node >= n) return;
  const int beg = rp[node], end = rp[node + 1];
  const size_t fo = (size_t)(lane << 1);
  float ax = 0.f, ay = 0.f;
  int e = beg;
  for (; e + 8 <= end; e += 8) {
    int2 q0 = cv[e + 0], q1 = cv[e + 1], q2 = cv[e + 2], q3 = cv[e + 3];
    int2 q4 = cv[e + 4], q5 = cv[e + 5], q6 = cv[e + 6], q7 = cv[e + 7];
    float2 x0 = *reinterpret_cast<const float2*>(h + (size_t)q0.x * HF + fo);
    float2 x1 = *reinterpret_cast<const float2*>(h + (size_t)q1.x * HF + fo);
    float2 x2 = *reinterpret_cast<const float2*>(h + (size_t)q2.x * HF + fo);
    float2 x3 = *reinterpret_cast<const float2*>(h + (size_t)q3.x * HF + fo);
    float2 x4 = *reinterpret_cast<const float2*>(h + (size_t)q4.x * HF + fo);
    float2 x5 = *reinterpret_cast<const float2*>(h + (size_t)q5.x * HF + fo);
    float2 x6 = *reinterpret_cast<const float2*>(h + (size_t)q6.x * HF + fo);
    float2 x7 = *reinterpret_cast<const float2*>(h + (size_t)q7.x * HF + fo);
    ax = fmaf(__int_as_float(q0.y), x0.x, ax); ay = fmaf(__int_as_float(q0.y), x0.y, ay);
    ax = fmaf(__int_as_float(q1.y), x1.x, ax); ay = fmaf(__int_as_float(q1.y), x1.y, ay);
    ax = fmaf(__int_as_float(q2.y), x2.x, ax); ay = fmaf(__int_as_float(q2.y), x2.y, ay);
    ax = fmaf(__int_as_float(q3.y), x3.x, ax); ay = fmaf(__int_as_float(q3.y), x3.y, ay);
    ax = fmaf(__int_as_float(q4.y), x4.x, ax); ay = fmaf(__int_as_float(q4.y), x4.y, ay);
    ax = fmaf(__int_as_float(q5.y), x5.x, ax); ay = fmaf(__int_as_float(q5.y), x5.y, ay);
    ax = fmaf(__int_as_float(q6.y), x6.x, ax); ay = fmaf(__int_as_float(q6.y), x6.y, ay);
    ax = fmaf(__int_as_float(q7.y), x7.x, ax); ay = fmaf(__int_as_float(q7.y), x7.y, ay);
  }
  if (e + 4 <= end) {
    int2 q0 = cv[e + 0], q1 = cv[e + 1], q2 = cv[e + 2], q3 = cv[e + 3];
    float2 x0 = *reinterpret_cast<const float2*>(h + (size_t)q0.x * HF + fo);
    float2 x1 = *reinterpret_cast<const float2*>(h + (size_t)q1.x * HF + fo);
    float2 x2 = *reinterpret_cast<const float2*>(h + (size_t)q2.x * HF + fo);
    float2 x3 = *reinterpret_cast<const float2*>(h + (size_t)q3.x * HF + fo);
    ax = fmaf(__int_as_float(q0.y), x0.x, ax); ay = fmaf(__int_as_float(q0.y), x0.y, ay);
    ax = fmaf(__int_as_float(q1.y), x1.x, ax); ay = fmaf(__int_as_float(q1.y), x1.y, ay);
    ax = fmaf(__int_as_float(q2.y), x2.x, ax); ay = fmaf(__int_as_float(q2.y), x2.y, ay);
    ax = fmaf(__int_as_float(q3.y), x3.x, ax); ay = fmaf(__int_as_float(q3.y), x3.y, ay);
    e += 4;
  }
  if (e + 2 <= end) {
    int2 q0 = cv[e + 0], q1 = cv[e + 1];
    float2 x0 = *reinterpret_cast<const float2*>(h + (size_t)q0.x * HF + fo);
    float2 x1 = *reinterpret_cast<const float2*>(h + (size_t)q1.x * HF + fo);
    ax = fmaf(__int_as_float(q0.y), x0.x, ax); ay = fmaf(__int_as_float(q0.y), x0.y, ay);
    ax = fmaf(__int_as_float(q1.y), x1.x, ax); ay = fmaf(__int_as_float(q1.y), x1.y, ay);
    e += 2;
  }
  if (e < end) {
    int2 q0 = cv[e];
    float2 x0 = *reinterpret_cast<const float2*>(h + (size_t)q0.x * HF + fo);
    ax = fmaf(__int_as_float(q0.y), x0.x, ax); ay = fmaf(__int_as_float(q0.y), x0.y, ay);
  }
  *reinterpret_cast<float2*>(agg + (size_t)node * HF + fo) = make_float2(ax, ay);
}

// fp32 register-tiled GEMM — EXACT round-10 structure (measured optimum: 51.4us,
// VALUBusy 48%, occ 35%, no spill). 64x128 tile, 256 threads, 4x8/thread, K-chunk 32,
// single-buffered global->LDS staging. Alternatives measured worse:
// 8x8@256=62.5 (grid-starved), reg-prefetch=124 (scratch spill), 8x8@128=66.4 (block-starved).
__global__ __launch_bounds__(256, 6) void k_gemm(const float* __restrict__ A, const float* __restrict__ W,
                                                 const float* __restrict__ bias, float* __restrict__ out, int n) {
  __shared__ float As[32][66];   // [k][node], stride 66 (8B-aligned rows, 2-way store alias)
  __shared__ float Ws[32][132];  // [k][col], pad (proven)
  const int tid = threadIdx.x;
  const int n0 = blockIdx.x * 64;
  const int ty = tid >> 4;  // 0..15 -> node quad ty*4
  const int tx = tid & 15;  // 0..15 -> col quads {tx*4, tx*4+64}
  float acc[4][8];
#pragma unroll
  for (int i = 0; i < 4; i++)
#pragma unroll
    for (int j = 0; j < 8; j++) acc[i][j] = 0.f;

  for (int kc = 0; kc < HF; kc += 32) {
    // A stage: 64 nodes x 32 k = 512 float4, 2 per thread
    {
      int node = tid >> 2;
      int ng = n0 + node;
#pragma unroll
      for (int i = 0; i < 2; ++i) {
        int kq = ((tid & 3) * 2 + i) * 4;
        float4 v = make_float4(0.f, 0.f, 0.f, 0.f);
        if (ng < n) v = *reinterpret_cast<const float4*>(A + (size_t)ng * HF + kc + kq);
        As[kq + 0][node] = v.x;
        As[kq + 1][node] = v.y;
        As[kq + 2][node] = v.z;
        As[kq + 3][node] = v.w;
      }
    }
    // W stage: 32 x 128 = 1024 float4, 4 per thread (proven map)
    {
      int c4 = (tid & 31) * 4;
      int r = tid >> 5;
#pragma unroll
      for (int p = 0; p < 4; ++p) {
        int rr = r + p * 8;
        *reinterpret_cast<float4*>(&Ws[rr][c4]) =
            *reinterpret_cast<const float4*>(W + (size_t)(kc + rr) * HF + c4);
      }
    }
    __syncthreads();
#pragma unroll
    for (int k = 0; k < 32; ++k) {
      float2 p0 = *reinterpret_cast<const float2*>(&As[k][ty * 4]);
      float2 p1 = *reinterpret_cast<const float2*>(&As[k][ty * 4 + 2]);
      float4 w0 = *reinterpret_cast<const float4*>(&Ws[k][tx * 4]);
      float4 w1 = *reinterpret_cast<const float4*>(&Ws[k][tx * 4 + 64]);
      float av[4] = {p0.x, p0.y, p1.x, p1.y};
      float wv[8] = {w0.x, w0.y, w0.z, w0.w, w1.x, w1.y, w1.z, w1.w};
#pragma unroll
      for (int i = 0; i < 4; i++)
#pragma unroll
        for (int j = 0; j < 8; j++) acc[i][j] = fmaf(av[i], wv[j], acc[i][j]);
    }
    __syncthreads();
  }

  float4 bb0 = *reinterpret_cast<const float4*>(bias + tx * 4);
  float4 bb1 = *reinterpret_cast<const float4*>(bias + tx * 4 + 64);
  float bb[8] = {bb0.x, bb0.y, bb0.z, bb0.w, bb1.x, bb1.y, bb1.z, bb1.w};
#pragma unroll
  for (int i = 0; i < 4; ++i) {
    int node = n0 + ty * 4 + i;
    if (node < n) {
      float o[8];
#pragma unroll
      for (int j = 0; j < 8; j++) o[j] = leaky(acc[i][j] + bb[j]);
      *reinterpret_cast<float4*>(out + (size_t)node * HF + tx * 4) = make_float4(o[0], o[1], o[2], o[3]);
      *reinterpret_cast<float4*>(out + (size_t)node * HF + tx * 4 + 64) = make_float4(o[4], o[5], o[6], o[7]);
    }
  }
}

// ---------------- head ----------------

__global__ __launch_bounds__(256) void k_head(const float* __restrict__ h, const float* __restrict__ fcW,
                                              const float* __restrict__ fcb, float* __restrict__ out, int n) {
  int gw = (blockIdx.x * 256 + threadIdx.x) >> 6;
  int lane = threadIdx.x & 63;
  int node = gw * 8 + (lane >> 3);
  int part = lane & 7;
  float a0 = 0.f, a1 = 0.f, a2 = 0.f, a3 = 0.f;
  if (node < n) {
    const float* hp = h + (size_t)node * HF + part * 16;
#pragma unroll
    for (int i = 0; i < 16; i++) {
      float xv = hp[i];
      float4 wk = *reinterpret_cast<const float4*>(fcW + (part * 16 + i) * 4);
      a0 = fmaf(xv, wk.x, a0);
      a1 = fmaf(xv, wk.y, a1);
      a2 = fmaf(xv, wk.z, a2);
      a3 = fmaf(xv, wk.w, a3);
    }
  }
#pragma unroll
  for (int m = 1; m < 8; m <<= 1) {
    a0 += __shfl_xor(a0, m, 64);
    a1 += __shfl_xor(a1, m, 64);
    a2 += __shfl_xor(a2, m, 64);
    a3 += __shfl_xor(a3, m, 64);
  }
  if (part == 0 && node < n) {
    float4 o = make_float4(a0 + fcb[0], a1 + fcb[1], a2 + fcb[2], a3 + fcb[3]);
    *reinterpret_cast<float4*>(out + (size_t)node * 4) = o;
  }
}

// ---------------- launch ----------------

extern "C" void kernel_launch(void* const* d_in, const int* in_sizes, int n_in,
                              void* d_out, int out_size, void* d_ws, size_t ws_size,
                              hipStream_t stream) {
  const float* x = (const float*)d_in[0];
  const float* ew = (const float*)d_in[1];
  const int* src = (const int*)d_in[2];
  const int* dst = (const int*)d_in[3];
  const float* W1 = (const float*)d_in[4];
  const float* b1 = (const float*)d_in[5];
  const float* Wst = (const float*)d_in[6];
  const float* bst = (const float*)d_in[7];
  const float* fcW = (const float*)d_in[8];
  const float* fcb = (const float*)d_in[9];
  float* out = (float*)d_out;

  const int n = NN, e = NE;
  char* w = (char*)d_ws;
  size_t off = 0;
  auto alloc = [&](size_t bytes) {
    void* p = w + off;
    off += (bytes + 511) & ~(size_t)511;
    return p;
  };
  int* dout = (int*)alloc((size_t)n * 4);
  int* din = (int*)alloc((size_t)n * 4);
  float* iso = (float*)alloc((size_t)n * 4);
  float* isi = (float*)alloc((size_t)n * 4);
  int* rp = (int*)alloc((size_t)(n + 1) * 4);
  int* cursor = (int*)alloc((size_t)n * 4);
  int* bsum = (int*)alloc((size_t)NB_SCAN * 4);
  int* boff = (int*)alloc((size_t)NB_SCAN * 4);
  int2* cv = (int2*)alloc((size_t)e * 8);
  float* h = (float*)alloc((size_t)n * HF * 4);
  float* agg = (float*)alloc((size_t)n * HF * 4);
  float* agg16 = agg;  // reuse

  hipMemsetAsync(dout, 0, (size_t)n * 4, stream);
  hipMemsetAsync(din, 0, (size_t)n * 4, stream);
  hipMemsetAsync(cursor, 0, (size_t)n * 4, stream);

  const int eh = 800000;  // e/2, multiple of 4
  k_deg1<<<idiv(eh, 1024), 256, 0, stream>>>(src, dout, 0, eh);
  k_deg1<<<idiv(e - eh, 1024), 256, 0, stream>>>(src, dout, eh, e);
  k_deg1<<<idiv(eh, 1024), 256, 0, stream>>>(dst, din, 0, eh);
  k_deg1<<<idiv(e - eh, 1024), 256, 0, stream>>>(dst, din, eh, e);
  k_norms<<<idiv(n, 256), 256, 0, stream>>>(dout, din, iso, isi, n);

  k_scan_part<<<NB_SCAN, 1024, 0, stream>>>(din, bsum, n);
  k_scan_small<<<1, 128, 0, stream>>>(bsum, boff, rp, n, NB_SCAN);
  k_scan_final<<<NB_SCAN, 1024, 0, stream>>>(din, boff, rp, n);

  k_build<<<idiv(eh, 256), 256, 0, stream>>>(src, dst, ew, iso, isi, rp, cursor, cv, 0, eh);
  k_build<<<idiv(e - eh, 256), 256, 0, stream>>>(src, dst, ew, iso, isi, rp, cursor, cv, eh, e);

  k_spmm16<<<idiv(n * INF, 256), 256, 0, stream>>>(x, rp, cv, agg16, n);
  k_gemm16<<<idiv(n * HF, 256), 256, 0, stream>>>(agg16, W1, b1, h, n);

  for (int l = 0; l < NLAYERS; ++l) {
    k_spmm<<<idiv(n, 4), 256, 0, stream>>>(h, rp, cv, agg, n);
    k_gemm<<<idiv(n, 64), 256, 0, stream>>>(agg, Wst + (size_t)l * HF * HF, bst + (size_t)l * HF, h, n);
  }
  k_head<<<idiv(n * 8, 256), 256, 0, stream>>>(h, fcW, fcb, out, n);
}

// Round 15
// 3235.884 us; speedup vs baseline: 1.1638x; 1.0525x over previous
//
#include <hip/hip_runtime.h>

#define NN 100000
#define NE 1600000
#define HF 128
#define INF 16
#define NLAYERS 19
#define NB_SCAN 98  // idiv(NN,1024)

static inline int idiv(int a, int b) { return (a + b - 1) / b; }

__device__ __forceinline__ float leaky(float v) { return (v >= 0.f) ? v : 0.01f * v; }

typedef __attribute__((ext_vector_type(8))) __bf16 bf16x8;
typedef __attribute__((ext_vector_type(4))) float f32x4;

__device__ __forceinline__ unsigned short rne_bf16(float x) {
  unsigned int u = __float_as_uint(x);
  unsigned int r = (u + 0x7fffu + ((u >> 16) & 1u)) >> 16;
  return (unsigned short)r;
}
__device__ __forceinline__ float bf2f(unsigned short h) {
  return __uint_as_float(((unsigned int)h) << 16);
}
__device__ __forceinline__ __bf16 bfbits(unsigned short h) {
  return __builtin_bit_cast(__bf16, h);
}

// ---------------- preprocessing ----------------

__global__ __launch_bounds__(256) void k_deg1(const int* __restrict__ idx, int* __restrict__ deg,
                                              int e0, int e1) {
  int i = e0 + (blockIdx.x * 256 + threadIdx.x) * 4;
  if (i + 4 <= e1) {
    int4 v = *reinterpret_cast<const int4*>(idx + i);
    atomicAdd(&deg[v.x], 1);
    atomicAdd(&deg[v.y], 1);
    atomicAdd(&deg[v.z], 1);
    atomicAdd(&deg[v.w], 1);
  } else {
    for (; i < e1; ++i) atomicAdd(&deg[idx[i]], 1);
  }
}

__global__ __launch_bounds__(256) void k_norms(const int* __restrict__ dout, const int* __restrict__ din,
                                               float* __restrict__ iso, float* __restrict__ isi, int n) {
  int i = blockIdx.x * 256 + threadIdx.x;
  if (i < n) {
    iso[i] = rsqrtf((float)(dout[i] > 1 ? dout[i] : 1));
    isi[i] = rsqrtf((float)(din[i] > 1 ? din[i] : 1));
  }
}

// ---- multi-block scan (3 kernels) ----

__global__ __launch_bounds__(1024) void k_scan_part(const int* __restrict__ cnt, int* __restrict__ bsum, int n) {
  __shared__ int wsum[16];
  const int tid = threadIdx.x;
  const int lane = tid & 63;
  const int wid = tid >> 6;
  int i = blockIdx.x * 1024 + tid;
  int v = (i < n) ? cnt[i] : 0;
  int s = v;
#pragma unroll
  for (int m = 1; m < 64; m <<= 1) s += __shfl_xor(s, m, 64);
  if (lane == 0) wsum[wid] = s;
  __syncthreads();
  if (tid == 0) {
    int t = 0;
#pragma unroll
    for (int j = 0; j < 16; j++) t += wsum[j];
    bsum[blockIdx.x] = t;
  }
}

__global__ __launch_bounds__(128) void k_scan_small(const int* __restrict__ bsum, int* __restrict__ boff,
                                                    int* __restrict__ rp, int n, int nb) {
  __shared__ int ws[2];
  const int tid = threadIdx.x;
  const int lane = tid & 63;
  const int wid = tid >> 6;
  int v = (tid < nb) ? bsum[tid] : 0;
  int x = v;
#pragma unroll
  for (int off = 1; off < 64; off <<= 1) {
    int t = __shfl_up(x, off, 64);
    if (lane >= off) x += t;
  }
  if (lane == 63) ws[wid] = x;
  __syncthreads();
  int add = (wid > 0) ? ws[0] : 0;
  if (tid < nb) boff[tid] = add + x - v;
  if (tid == 127) rp[n] = ws[0] + x;
}

__global__ __launch_bounds__(1024) void k_scan_final(const int* __restrict__ cnt, const int* __restrict__ boff,
                                                     int* __restrict__ rp, int n) {
  __shared__ int wsum[16];
  const int tid = threadIdx.x;
  const int lane = tid & 63;
  const int wid = tid >> 6;
  int i = blockIdx.x * 1024 + tid;
  int v = (i < n) ? cnt[i] : 0;
  int x = v;
#pragma unroll
  for (int off = 1; off < 64; off <<= 1) {
    int t = __shfl_up(x, off, 64);
    if (lane >= off) x += t;
  }
  if (lane == 63) wsum[wid] = x;
  __syncthreads();
  if (wid == 0) {
    int s = (lane < 16) ? wsum[lane] : 0;
#pragma unroll
    for (int off = 1; off < 16; off <<= 1) {
      int t = __shfl_up(s, off, 64);
      if (lane >= off) s += t;
    }
    if (lane < 16) wsum[lane] = s;
  }
  __syncthreads();
  int woff = (wid > 0) ? wsum[wid - 1] : 0;
  if (i < n) rp[i] = boff[blockIdx.x] + woff + x - v;
}

// build packed CSR over edge range [e0,e1): cv[pos] = {col, bits(val)}
__global__ __launch_bounds__(256) void k_build(const int* __restrict__ src, const int* __restrict__ dst,
                                               const float* __restrict__ ew, const float* __restrict__ iso,
                                               const float* __restrict__ isi, const int* __restrict__ rp,
                                               int* __restrict__ cursor, int2* __restrict__ cv,
                                               int e0, int e1) {
  int i = e0 + blockIdx.x * 256 + threadIdx.x;
  if (i < e1) {
    int s = src[i], d = dst[i];
    int pos = rp[d] + atomicAdd(&cursor[d], 1);
    float v = ew[i] * iso[s] * isi[d];
    cv[pos] = make_int2(s, __float_as_int(v));
  }
}

// W pre-split: W[k][c] fp32 -> 3 bf16 planes in MFMA-fragment order.
// Layout (bf16 units, per layer, 49152 total):
//   off(p,kc,t,l,i) = p*16384 + kc*4096 + t*512 + l*8 + i
// with logical k = kc*32 + (l>>4)*8 + i, col = t*16 + (l&15).
// (k-permutation within lane-groups is free as long as A uses the same one.)
__global__ __launch_bounds__(256) void k_wsplit(const float* __restrict__ Wst, unsigned short* __restrict__ W3,
                                                int nlayers) {
  int g = blockIdx.x * 256 + threadIdx.x;
  int lane = g & 63;
  int fid = g >> 6;
  if (fid >= nlayers * 32) return;
  int layer = fid >> 5;
  int rem = fid & 31;
  int kc = rem >> 3;
  int t8 = rem & 7;
  const float* W = Wst + (size_t)layer * HF * HF;
  int col = t8 * 16 + (lane & 15);
  int krow = kc * 32 + (lane >> 4) * 8;
  unsigned int o1[4], o2[4], o3[4];
#pragma unroll
  for (int i = 0; i < 4; ++i) {
    float xa = W[(size_t)(krow + 2 * i) * HF + col];
    float xb = W[(size_t)(krow + 2 * i + 1) * HF + col];
    unsigned short a1 = rne_bf16(xa); float ra1 = xa - bf2f(a1);
    unsigned short a2 = rne_bf16(ra1); float ra2 = ra1 - bf2f(a2);
    unsigned short a3 = rne_bf16(ra2);
    unsigned short b1 = rne_bf16(xb); float rb1 = xb - bf2f(b1);
    unsigned short b2 = rne_bf16(rb1); float rb2 = rb1 - bf2f(b2);
    unsigned short b3 = rne_bf16(rb2);
    o1[i] = (unsigned)a1 | ((unsigned)b1 << 16);
    o2[i] = (unsigned)a2 | ((unsigned)b2 << 16);
    o3[i] = (unsigned)a3 | ((unsigned)b3 << 16);
  }
  size_t base = (size_t)layer * 49152 + (size_t)kc * 4096 + (size_t)t8 * 512 + (size_t)lane * 8;
  *reinterpret_cast<uint4*>(W3 + base)         = make_uint4(o1[0], o1[1], o1[2], o1[3]);
  *reinterpret_cast<uint4*>(W3 + base + 16384) = make_uint4(o2[0], o2[1], o2[2], o2[3]);
  *reinterpret_cast<uint4*>(W3 + base + 32768) = make_uint4(o3[0], o3[1], o3[2], o3[3]);
}

// ---------------- layer 1 (16 feats) ----------------

__global__ __launch_bounds__(256) void k_spmm16(const float* __restrict__ x, const int* __restrict__ rp,
                                                const int2* __restrict__ cv, float* __restrict__ agg16, int n) {
  int t = blockIdx.x * 256 + threadIdx.x;
  int node = t >> 4, f = t & 15;
  if (node >= n) return;
  int e = rp[node], end = rp[node + 1];
  float a = 0.f;
  for (; e + 4 <= end; e += 4) {
    int2 q0 = cv[e], q1 = cv[e + 1], q2 = cv[e + 2], q3 = cv[e + 3];
    float x0 = x[(size_t)q0.x * INF + f];
    float x1 = x[(size_t)q1.x * INF + f];
    float x2 = x[(size_t)q2.x * INF + f];
    float x3 = x[(size_t)q3.x * INF + f];
    a = fmaf(__int_as_float(q0.y), x0, a);
    a = fmaf(__int_as_float(q1.y), x1, a);
    a = fmaf(__int_as_float(q2.y), x2, a);
    a = fmaf(__int_as_float(q3.y), x3, a);
  }
  for (; e < end; ++e) {
    int2 q = cv[e];
    a = fmaf(__int_as_float(q.y), x[(size_t)q.x * INF + f], a);
  }
  agg16[(size_t)node * INF + f] = a;
}

__global__ __launch_bounds__(256) void k_gemm16(const float* __restrict__ agg16, const float* __restrict__ W1,
                                                const float* __restrict__ b1, float* __restrict__ h, int n) {
  __shared__ float W1s[INF * HF];
  int tid = threadIdx.x;
  {
    float4* d4 = reinterpret_cast<float4*>(W1s);
    const float4* s4 = reinterpret_cast<const float4*>(W1);
    d4[tid] = s4[tid];
    d4[tid + 256] = s4[tid + 256];
  }
  __syncthreads();
  int t = blockIdx.x * 256 + tid;
  int node = t >> 7, c = t & 127;
  if (node >= n) return;
  const float* ar = agg16 + (size_t)node * INF;
  float4 a0 = *reinterpret_cast<const float4*>(ar);
  float4 a1 = *reinterpret_cast<const float4*>(ar + 4);
  float4 a2 = *reinterpret_cast<const float4*>(ar + 8);
  float4 a3 = *reinterpret_cast<const float4*>(ar + 12);
  float av[16] = {a0.x, a0.y, a0.z, a0.w, a1.x, a1.y, a1.z, a1.w,
                  a2.x, a2.y, a2.z, a2.w, a3.x, a3.y, a3.z, a3.w};
  float a = b1[c];
#pragma unroll
  for (int f = 0; f < INF; ++f) a = fmaf(av[f], W1s[f * HF + c], a);
  h[(size_t)t] = leaky(a);
}

// ---------------- hidden layers ----------------

// wave-per-node, float2 per lane, 8-deep gather pipeline (at fabric BW ceiling).
__global__ __launch_bounds__(256) void k_spmm(const float* __restrict__ h, const int* __restrict__ rp,
                                              const int2* __restrict__ cv, float* __restrict__ agg, int n) {
  const int lane = threadIdx.x & 63;
  const int node = __builtin_amdgcn_readfirstlane(blockIdx.x * 4 + (threadIdx.x >> 6));
  if (node >= n) return;
  const int beg = rp[node], end = rp[node + 1];
  const size_t fo = (size_t)(lane << 1);
  float ax = 0.f, ay = 0.f;
  int e = beg;
  for (; e + 8 <= end; e += 8) {
    int2 q0 = cv[e + 0], q1 = cv[e + 1], q2 = cv[e + 2], q3 = cv[e + 3];
    int2 q4 = cv[e + 4], q5 = cv[e + 5], q6 = cv[e + 6], q7 = cv[e + 7];
    float2 x0 = *reinterpret_cast<const float2*>(h + (size_t)q0.x * HF + fo);
    float2 x1 = *reinterpret_cast<const float2*>(h + (size_t)q1.x * HF + fo);
    float2 x2 = *reinterpret_cast<const float2*>(h + (size_t)q2.x * HF + fo);
    float2 x3 = *reinterpret_cast<const float2*>(h + (size_t)q3.x * HF + fo);
    float2 x4 = *reinterpret_cast<const float2*>(h + (size_t)q4.x * HF + fo);
    float2 x5 = *reinterpret_cast<const float2*>(h + (size_t)q5.x * HF + fo);
    float2 x6 = *reinterpret_cast<const float2*>(h + (size_t)q6.x * HF + fo);
    float2 x7 = *reinterpret_cast<const float2*>(h + (size_t)q7.x * HF + fo);
    ax = fmaf(__int_as_float(q0.y), x0.x, ax); ay = fmaf(__int_as_float(q0.y), x0.y, ay);
    ax = fmaf(__int_as_float(q1.y), x1.x, ax); ay = fmaf(__int_as_float(q1.y), x1.y, ay);
    ax = fmaf(__int_as_float(q2.y), x2.x, ax); ay = fmaf(__int_as_float(q2.y), x2.y, ay);
    ax = fmaf(__int_as_float(q3.y), x3.x, ax); ay = fmaf(__int_as_float(q3.y), x3.y, ay);
    ax = fmaf(__int_as_float(q4.y), x4.x, ax); ay = fmaf(__int_as_float(q4.y), x4.y, ay);
    ax = fmaf(__int_as_float(q5.y), x5.x, ax); ay = fmaf(__int_as_float(q5.y), x5.y, ay);
    ax = fmaf(__int_as_float(q6.y), x6.x, ax); ay = fmaf(__int_as_float(q6.y), x6.y, ay);
    ax = fmaf(__int_as_float(q7.y), x7.x, ax); ay = fmaf(__int_as_float(q7.y), x7.y, ay);
  }
  if (e + 4 <= end) {
    int2 q0 = cv[e + 0], q1 = cv[e + 1], q2 = cv[e + 2], q3 = cv[e + 3];
    float2 x0 = *reinterpret_cast<const float2*>(h + (size_t)q0.x * HF + fo);
    float2 x1 = *reinterpret_cast<const float2*>(h + (size_t)q1.x * HF + fo);
    float2 x2 = *reinterpret_cast<const float2*>(h + (size_t)q2.x * HF + fo);
    float2 x3 = *reinterpret_cast<const float2*>(h + (size_t)q3.x * HF + fo);
    ax = fmaf(__int_as_float(q0.y), x0.x, ax); ay = fmaf(__int_as_float(q0.y), x0.y, ay);
    ax = fmaf(__int_as_float(q1.y), x1.x, ax); ay = fmaf(__int_as_float(q1.y), x1.y, ay);
    ax = fmaf(__int_as_float(q2.y), x2.x, ax); ay = fmaf(__int_as_float(q2.y), x2.y, ay);
    ax = fmaf(__int_as_float(q3.y), x3.x, ax); ay = fmaf(__int_as_float(q3.y), x3.y, ay);
    e += 4;
  }
  if (e + 2 <= end) {
    int2 q0 = cv[e + 0], q1 = cv[e + 1];
    float2 x0 = *reinterpret_cast<const float2*>(h + (size_t)q0.x * HF + fo);
    float2 x1 = *reinterpret_cast<const float2*>(h + (size_t)q1.x * HF + fo);
    ax = fmaf(__int_as_float(q0.y), x0.x, ax); ay = fmaf(__int_as_float(q0.y), x0.y, ay);
    ax = fmaf(__int_as_float(q1.y), x1.x, ax); ay = fmaf(__int_as_float(q1.y), x1.y, ay);
    e += 2;
  }
  if (e < end) {
    int2 q0 = cv[e];
    float2 x0 = *reinterpret_cast<const float2*>(h + (size_t)q0.x * HF + fo);
    ax = fmaf(__int_as_float(q0.y), x0.x, ax); ay = fmaf(__int_as_float(q0.y), x0.y, ay);
  }
  *reinterpret_cast<float2*>(agg + (size_t)node * HF + fo) = make_float2(ax, ay);
}

// MFMA split-3 GEMM: out = leaky(A @ W + b), fp32-equivalent via 6 bf16 products.
// Block = 64 nodes x 128 cols, 4 waves; wave w -> nodes [n0+w*16, +16).
// Per wave: 8 output tiles 16x16, K=128 in 4 chunks of 32 (mfma_f32_16x16x32_bf16).
// A split in-register from global (L2-hot agg); W pre-split (k_wsplit) staged to LDS.
// Fragment k-mapping: k = kc*32 + (lane>>4)*8 + i for BOTH A and B (free permutation).
// C/D layout (m89-verified): col = lane&15, row = (lane>>4)*4 + reg.
__global__ __launch_bounds__(256) void k_mfma(const float* __restrict__ A, const unsigned short* __restrict__ W3L,
                                              const float* __restrict__ bias, float* __restrict__ out, int n) {
  __shared__ unsigned short WB[3 * 4096];  // 3 planes x (8 tiles x 64 lanes x 8 elems)
  const int tid = threadIdx.x;
  const int w = tid >> 6;
  const int l = tid & 63;
  const int n0 = blockIdx.x * 64;
  const int m15 = l & 15;
  const int g4 = l >> 4;

  const int nodeA = n0 + w * 16 + m15;
  const bool aok = nodeA < n;
  const float* ap = A + (size_t)nodeA * HF + g4 * 8;

  f32x4 acc[8];
#pragma unroll
  for (int t = 0; t < 8; ++t) acc[t] = (f32x4){0.f, 0.f, 0.f, 0.f};

  float4* WB4 = reinterpret_cast<float4*>(WB);
  const float4* G4 = reinterpret_cast<const float4*>(W3L);

  for (int kc = 0; kc < 4; ++kc) {
    // A loads for this chunk (independent of LDS; overlap with staging)
    float4 fA = make_float4(0.f, 0.f, 0.f, 0.f);
    float4 fB = make_float4(0.f, 0.f, 0.f, 0.f);
    if (aok) {
      fA = *reinterpret_cast<const float4*>(ap + kc * 32);
      fB = *reinterpret_cast<const float4*>(ap + kc * 32 + 4);
    }
    // stage W chunk: 3 planes x 512 float4 = 24KB, coalesced linear copy
#pragma unroll
    for (int s = 0; s < 6; ++s) {
      int lin = s * 256 + tid;
      int p = lin >> 9;
      int off = lin & 511;
      WB4[lin] = G4[(p * 4 + kc) * 512 + off];
    }
    __syncthreads();
    // split A into 3 bf16 fragments (exact residual split)
    bf16x8 fa1, fa2, fa3;
    {
      float xs[8] = {fA.x, fA.y, fA.z, fA.w, fB.x, fB.y, fB.z, fB.w};
#pragma unroll
      for (int i = 0; i < 8; ++i) {
        float x = xs[i];
        unsigned short h1 = rne_bf16(x);
        float r1 = x - bf2f(h1);
        unsigned short h2 = rne_bf16(r1);
        float r2 = r1 - bf2f(h2);
        unsigned short h3 = rne_bf16(r2);
        fa1[i] = bfbits(h1);
        fa2[i] = bfbits(h2);
        fa3[i] = bfbits(h3);
      }
    }
    const bf16x8* WBv = reinterpret_cast<const bf16x8*>(WB);
#pragma unroll
    for (int t = 0; t < 8; ++t) {
      bf16x8 b1 = WBv[t * 64 + l];
      bf16x8 b2 = WBv[512 + t * 64 + l];
      bf16x8 b3 = WBv[1024 + t * 64 + l];
      acc[t] = __builtin_amdgcn_mfma_f32_16x16x32_bf16(fa1, b1, acc[t], 0, 0, 0);
      acc[t] = __builtin_amdgcn_mfma_f32_16x16x32_bf16(fa1, b2, acc[t], 0, 0, 0);
      acc[t] = __builtin_amdgcn_mfma_f32_16x16x32_bf16(fa2, b1, acc[t], 0, 0, 0);
      acc[t] = __builtin_amdgcn_mfma_f32_16x16x32_bf16(fa2, b2, acc[t], 0, 0, 0);
      acc[t] = __builtin_amdgcn_mfma_f32_16x16x32_bf16(fa1, b3, acc[t], 0, 0, 0);
      acc[t] = __builtin_amdgcn_mfma_f32_16x16x32_bf16(fa3, b1, acc[t], 0, 0, 0);
    }
    __syncthreads();
  }

  // epilogue: D[row=(l>>4)*4+r][col=l&15] per tile
  const int baserow = n0 + w * 16 + g4 * 4;
#pragma unroll
  for (int t = 0; t < 8; ++t) {
    int col = t * 16 + m15;
    float bb = bias[col];
#pragma unroll
    for (int r = 0; r < 4; ++r) {
      int node = baserow + r;
      if (node < n) out[(size_t)node * HF + col] = leaky(acc[t][r] + bb);
    }
  }
}

// ---------------- head ----------------

__global__ __launch_bounds__(256) void k_head(const float* __restrict__ h, const float* __restrict__ fcW,
                                              const float* __restrict__ fcb, float* __restrict__ out, int n) {
  int gw = (blockIdx.x * 256 + threadIdx.x) >> 6;
  int lane = threadIdx.x & 63;
  int node = gw * 8 + (lane >> 3);
  int part = lane & 7;
  float a0 = 0.f, a1 = 0.f, a2 = 0.f, a3 = 0.f;
  if (node < n) {
    const float* hp = h + (size_t)node * HF + part * 16;
#pragma unroll
    for (int i = 0; i < 16; i++) {
      float xv = hp[i];
      float4 wk = *reinterpret_cast<const float4*>(fcW + (part * 16 + i) * 4);
      a0 = fmaf(xv, wk.x, a0);
      a1 = fmaf(xv, wk.y, a1);
      a2 = fmaf(xv, wk.z, a2);
      a3 = fmaf(xv, wk.w, a3);
    }
  }
#pragma unroll
  for (int m = 1; m < 8; m <<= 1) {
    a0 += __shfl_xor(a0, m, 64);
    a1 += __shfl_xor(a1, m, 64);
    a2 += __shfl_xor(a2, m, 64);
    a3 += __shfl_xor(a3, m, 64);
  }
  if (part == 0 && node < n) {
    float4 o = make_float4(a0 + fcb[0], a1 + fcb[1], a2 + fcb[2], a3 + fcb[3]);
    *reinterpret_cast<float4*>(out + (size_t)node * 4) = o;
  }
}

// ---------------- launch ----------------

extern "C" void kernel_launch(void* const* d_in, const int* in_sizes, int n_in,
                              void* d_out, int out_size, void* d_ws, size_t ws_size,
                              hipStream_t stream) {
  const float* x = (const float*)d_in[0];
  const float* ew = (const float*)d_in[1];
  const int* src = (const int*)d_in[2];
  const int* dst = (const int*)d_in[3];
  const float* W1 = (const float*)d_in[4];
  const float* b1 = (const float*)d_in[5];
  const float* Wst = (const float*)d_in[6];
  const float* bst = (const float*)d_in[7];
  const float* fcW = (const float*)d_in[8];
  const float* fcb = (const float*)d_in[9];
  float* out = (float*)d_out;

  const int n = NN, e = NE;
  char* w = (char*)d_ws;
  size_t off = 0;
  auto alloc = [&](size_t bytes) {
    void* p = w + off;
    off += (bytes + 511) & ~(size_t)511;
    return p;
  };
  int* dout = (int*)alloc((size_t)n * 4);
  int* din = (int*)alloc((size_t)n * 4);
  float* iso = (float*)alloc((size_t)n * 4);
  float* isi = (float*)alloc((size_t)n * 4);
  int* rp = (int*)alloc((size_t)(n + 1) * 4);
  int* cursor = (int*)alloc((size_t)n * 4);
  int* bsum = (int*)alloc((size_t)NB_SCAN * 4);
  int* boff = (int*)alloc((size_t)NB_SCAN * 4);
  unsigned short* W3 = (unsigned short*)alloc((size_t)NLAYERS * 49152 * 2);
  int2* cv = (int2*)alloc((size_t)e * 8);
  float* h = (float*)alloc((size_t)n * HF * 4);
  float* agg = (float*)alloc((size_t)n * HF * 4);
  float* agg16 = agg;  // reuse

  hipMemsetAsync(dout, 0, (size_t)n * 4, stream);
  hipMemsetAsync(din, 0, (size_t)n * 4, stream);
  hipMemsetAsync(cursor, 0, (size_t)n * 4, stream);

  k_wsplit<<<idiv(NLAYERS * 32 * 64, 256), 256, 0, stream>>>(Wst, W3, NLAYERS);

  const int eh = 800000;  // e/2, multiple of 4
  k_deg1<<<idiv(eh, 1024), 256, 0, stream>>>(src, dout, 0, eh);
  k_deg1<<<idiv(e - eh, 1024), 256, 0, stream>>>(src, dout, eh, e);
  k_deg1<<<idiv(eh, 1024), 256, 0, stream>>>(dst, din, 0, eh);
  k_deg1<<<idiv(e - eh, 1024), 256, 0, stream>>>(dst, din, eh, e);
  k_norms<<<idiv(n, 256), 256, 0, stream>>>(dout, din, iso, isi, n);

  k_scan_part<<<NB_SCAN, 1024, 0, stream>>>(din, bsum, n);
  k_scan_small<<<1, 128, 0, stream>>>(bsum, boff, rp, n, NB_SCAN);
  k_scan_final<<<NB_SCAN, 1024, 0, stream>>>(din, boff, rp, n);

  k_build<<<idiv(eh, 256), 256, 0, stream>>>(src, dst, ew, iso, isi, rp, cursor, cv, 0, eh);
  k_build<<<idiv(e - eh, 256), 256, 0, stream>>>(src, dst, ew, iso, isi, rp, cursor, cv, eh, e);

  k_spmm16<<<idiv(n * INF, 256), 256, 0, stream>>>(x, rp, cv, agg16, n);
  k_gemm16<<<idiv(n * HF, 256), 256, 0, stream>>>(agg16, W1, b1, h, n);

  for (int l = 0; l < NLAYERS; ++l) {
    k_spmm<<<idiv(n, 4), 256, 0, stream>>>(h, rp, cv, agg, n);
    k_mfma<<<idiv(n, 64), 256, 0, stream>>>(agg, W3 + (size_t)l * 49152, bst + (size_t)l * HF, h, n);
  }
  k_head<<<idiv(n * 8, 256), 256, 0, stream>>>(h, fcW, fcb, out, n);
}